// Round 8
// baseline (2672.343 us; speedup 1.0000x reference)
//
#include <hip/hip_runtime.h>
#include <stdint.h>

// ---------------------------------------------------------------------------
// HierarchicalReasoningEncoder on MI355X (gfx950).
// fp32 I/O. GEMMs: LDS-staged 128x128xBK32 tiles, hi/lo-split bf16 MFMA.
// Recurrence: register-resident W_hh (bf16) + MFMA gates; h fp32 in LDS.
// R8: gru_reg register-pressure fix — xp staged via global_load_lds DMA
// (zero VGPRs), deferred packed output stores (drain overlaps MFMA), so
// wf[48] + acc[6] fit under the 256-reg/wave cap (8-wave WG, 2 waves/SIMD).
// ---------------------------------------------------------------------------

using uint32  = unsigned int;
using bf16x8  = __attribute__((ext_vector_type(8))) __bf16;
using floatx4 = __attribute__((ext_vector_type(4))) float;

union U4B { uint4 u; bf16x8 v; };

__device__ __forceinline__ float b2f(unsigned short u) {
    union { uint32 i; float f; } v; v.i = ((uint32)u) << 16; return v.f;
}
__device__ __forceinline__ unsigned short f2b(float f) {
    union { float f; uint32 i; } v; v.f = f;
    uint32 r = v.i + 0x7fffu + ((v.i >> 16) & 1u);   // RNE
    return (unsigned short)(r >> 16);
}
__device__ __forceinline__ float sigmoidf_(float x) { return 1.f / (1.f + __expf(-x)); }
__device__ __forceinline__ float tanhf_(float x) {
    x = fminf(15.f, fmaxf(-15.f, x));
    float e = __expf(2.f * x);
    return (e - 1.f) / (e + 1.f);
}

// ---------------------------------------------------------------------------
// Workspace layout (bytes). Total ~130.7 MB.
// ---------------------------------------------------------------------------
#define O_XPC     0L            // 2*256*32*768*4 = 50331648 (chunked xp, fp32)
#define O_OWHI    50331648L     // 32768*512*2 = 33554432
#define O_OWLO    83886080L
#define O_STATE   117440512L    // 2*256*256*4 = 524288
#define O_SCW     117964800L    // 32768*4 = 131072
#define O_W0HI    118095872L
#define O_W0LO    118882304L
#define O_W1HI    119668736L
#define O_W1LO    120455168L
#define O_WAHI    121241600L
#define O_WALO    121765888L
#define O_S0HI    122290176L
#define O_S0LO    123076608L
#define O_S1HI    123863040L
#define O_S1LO    124649472L
#define O_SAHI    125435904L
#define O_SALO    125960192L
#define O_HW0     126484480L    // W_hh bf16 (393216 B each)
#define O_HW1     126877696L
#define O_HS0     127270912L
#define O_HS1     127664128L
#define O_SENTHI  128057344L
#define O_SENTLO  128319488L
#define O_XPS     128581632L    // 2*16*16*768*4 = 1572864
#define O_SSTATE  130154496L    // 2*16*256*4 = 32768
#define O_OSHI    130187264L
#define O_OSLO    130449408L
#define O_SCS     130711552L

// ---------------------------------------------------------------------------
// Weight prep: fp32 -> bf16 hi/lo, 6 matrices, one launch.
// ---------------------------------------------------------------------------
__global__ __launch_bounds__(256)
void cvt_hilo6(const float* __restrict__ s0, const float* __restrict__ s1,
               const float* __restrict__ s2, const float* __restrict__ s3,
               const float* __restrict__ s4, const float* __restrict__ s5,
               char* __restrict__ ws)
{
    const int b = blockIdx.x;
    const float* src; unsigned short *hi, *lo; int base;
    if (b < 192)      { src = s0; hi = (unsigned short*)(ws + O_W0HI); lo = (unsigned short*)(ws + O_W0LO); base = b; }
    else if (b < 384) { src = s1; hi = (unsigned short*)(ws + O_W1HI); lo = (unsigned short*)(ws + O_W1LO); base = b - 192; }
    else if (b < 576) { src = s2; hi = (unsigned short*)(ws + O_S0HI); lo = (unsigned short*)(ws + O_S0LO); base = b - 384; }
    else if (b < 768) { src = s3; hi = (unsigned short*)(ws + O_S1HI); lo = (unsigned short*)(ws + O_S1LO); base = b - 576; }
    else if (b < 896) { src = s4; hi = (unsigned short*)(ws + O_WAHI); lo = (unsigned short*)(ws + O_WALO); base = b - 768; }
    else              { src = s5; hi = (unsigned short*)(ws + O_SAHI); lo = (unsigned short*)(ws + O_SALO); base = b - 896; }
    const int idx = (base * 256 + threadIdx.x) * 8;
    float f[8];
    *reinterpret_cast<float4*>(&f[0]) = *reinterpret_cast<const float4*>(src + idx);
    *reinterpret_cast<float4*>(&f[4]) = *reinterpret_cast<const float4*>(src + idx + 4);
    unsigned short h[8], l[8];
    #pragma unroll
    for (int j = 0; j < 8; ++j) {
        h[j] = f2b(f[j]);
        l[j] = f2b(f[j] - b2f(h[j]));
    }
    *reinterpret_cast<uint4*>(hi + idx) = *reinterpret_cast<const uint4*>(h);
    *reinterpret_cast<uint4*>(lo + idx) = *reinterpret_cast<const uint4*>(l);
}

// W_hh fp32 -> single bf16, 4 matrices, one launch.
__global__ __launch_bounds__(256)
void cvt_b4(const float* __restrict__ s0, const float* __restrict__ s1,
            const float* __restrict__ s2, const float* __restrict__ s3,
            char* __restrict__ ws)
{
    const int b = blockIdx.x;
    const float* src; unsigned short* dst; int base;
    if (b < 96)       { src = s0; dst = (unsigned short*)(ws + O_HW0); base = b; }
    else if (b < 192) { src = s1; dst = (unsigned short*)(ws + O_HW1); base = b - 96; }
    else if (b < 288) { src = s2; dst = (unsigned short*)(ws + O_HS0); base = b - 192; }
    else              { src = s3; dst = (unsigned short*)(ws + O_HS1); base = b - 288; }
    const int idx = (base * 256 + threadIdx.x) * 8;
    float f[8];
    *reinterpret_cast<float4*>(&f[0]) = *reinterpret_cast<const float4*>(src + idx);
    *reinterpret_cast<float4*>(&f[4]) = *reinterpret_cast<const float4*>(src + idx + 4);
    unsigned short o[8];
    #pragma unroll
    for (int j = 0; j < 8; ++j) o[j] = f2b(f[j]);
    *reinterpret_cast<uint4*>(dst + idx) = *reinterpret_cast<const uint4*>(o);
}

// ---------------------------------------------------------------------------
// A-row remap (element offset into the A array, row length 512).
// ---------------------------------------------------------------------------
template<int AMODE>
__device__ __forceinline__ long amap(int m, int t0, int sgn) {
    if (AMODE == 1) {
        const int n = m >> 5, tl = m & 31;
        const int t = t0 + sgn * tl;
        return ((long)((n & 15) * 128 + t) * 16 + (n >> 4)) * 512;
    } else if (AMODE == 3) {
        const int n = m >> 4, tl = m & 15;
        return (long)(n * 16 + t0 + sgn * tl) * 512;
    }
    return (long)m * 512;
}

// ---------------------------------------------------------------------------
// LDS-staged GEMM (unchanged from R7): 128x128 tile, BK=32, 4 waves 2x2.
// ---------------------------------------------------------------------------
template<int AMODE, int OUT>
__global__ __launch_bounds__(256)
void gemm_lds(const void* __restrict__ Ap, const void* __restrict__ Ap2,
              const unsigned short* __restrict__ Whi, const unsigned short* __restrict__ Wlo,
              const float* __restrict__ bias,
              float* __restrict__ C, int ldC,
              float* __restrict__ score, const float* __restrict__ ctx,
              int t0, int sgn)
{
    __shared__ char smem_[32768];

    int bx = blockIdx.x, by = blockIdx.y;
    {
        const int nbx = gridDim.x, nby = gridDim.y;
        if ((nby & 7) == 0) {
            const int l = by * nbx + bx;      // hardware-linear id (x fastest)
            const int xcd = l & 7;
            const int s = l >> 3;
            bx = s % nbx;
            by = xcd * (nby >> 3) + s / nbx;
        }
    }

    const int tid  = threadIdx.x;
    const int lane = tid & 63;
    const int wave = tid >> 6;
    const int wm = wave >> 1, wn = wave & 1;
    const int m_base = by * 128;
    const int n_base = bx * 128;
    const int q = lane >> 4;
    const int r = lane & 15;

    float* As = (float*)smem_;
    unsigned short* Ahs = (unsigned short*)smem_;
    unsigned short* Als = (unsigned short*)(smem_ + 8192);
    unsigned short* Whs = (unsigned short*)(smem_ + 16384);
    unsigned short* Wls = (unsigned short*)(smem_ + 24576);

    int wslot[2]; long wgoff[2];
    #pragma unroll
    for (int i = 0; i < 2; ++i) {
        const int idx = tid + 256 * i;
        const int rr = idx >> 2, kg = idx & 3;
        wslot[i] = rr * 4 + ((kg + rr) & 3);
        wgoff[i] = (long)(n_base + rr) * 512 + kg * 8;
    }
    int aslot1[4]; long agoff1[4];
    int aslot2[2]; long agoff2[2];
    if (AMODE == 1) {
        #pragma unroll
        for (int i = 0; i < 4; ++i) {
            const int idx = tid + 256 * i;
            const int rr = idx >> 3, kg = idx & 7;
            aslot1[i] = rr * 8 + ((kg + rr) & 7);
            agoff1[i] = amap<AMODE>(m_base + rr, t0, sgn) + kg * 4;
        }
    } else {
        #pragma unroll
        for (int i = 0; i < 2; ++i) {
            const int idx = tid + 256 * i;
            const int rr = idx >> 2, kg = idx & 3;
            aslot2[i] = rr * 4 + ((kg + rr) & 3);
            agoff2[i] = amap<AMODE>(m_base + rr, t0, sgn) + kg * 8;
        }
    }

    floatx4 acc[4][4];
    #pragma unroll
    for (int mt = 0; mt < 4; ++mt)
        #pragma unroll
        for (int nt = 0; nt < 4; ++nt) acc[mt][nt] = (floatx4){0.f, 0.f, 0.f, 0.f};

    for (int k0 = 0; k0 < 512; k0 += 32) {
        uint4 wbh[2], wbl[2], ab[4];
        #pragma unroll
        for (int i = 0; i < 2; ++i) {
            wbh[i] = *reinterpret_cast<const uint4*>(Whi + wgoff[i] + k0);
            wbl[i] = *reinterpret_cast<const uint4*>(Wlo + wgoff[i] + k0);
        }
        if (AMODE == 1) {
            const float* A = (const float*)Ap;
            #pragma unroll
            for (int i = 0; i < 4; ++i)
                ab[i] = *reinterpret_cast<const uint4*>(A + agoff1[i] + k0);
        } else {
            const unsigned short* Ahi = (const unsigned short*)Ap;
            const unsigned short* Alo = (const unsigned short*)Ap2;
            #pragma unroll
            for (int i = 0; i < 2; ++i) {
                ab[i]     = *reinterpret_cast<const uint4*>(Ahi + agoff2[i] + k0);
                ab[2 + i] = *reinterpret_cast<const uint4*>(Alo + agoff2[i] + k0);
            }
        }
        __syncthreads();
        #pragma unroll
        for (int i = 0; i < 2; ++i) {
            *reinterpret_cast<uint4*>(Whs + wslot[i] * 8) = wbh[i];
            *reinterpret_cast<uint4*>(Wls + wslot[i] * 8) = wbl[i];
        }
        if (AMODE == 1) {
            #pragma unroll
            for (int i = 0; i < 4; ++i)
                *reinterpret_cast<uint4*>(As + aslot1[i] * 4) = ab[i];
        } else {
            #pragma unroll
            for (int i = 0; i < 2; ++i) {
                *reinterpret_cast<uint4*>(Ahs + aslot2[i] * 8) = ab[i];
                *reinterpret_cast<uint4*>(Als + aslot2[i] * 8) = ab[2 + i];
            }
        }
        __syncthreads();

        bf16x8 ah[4], al[4];
        #pragma unroll
        for (int mt = 0; mt < 4; ++mt) {
            const int R = wm * 64 + mt * 16 + r;
            if (AMODE == 1) {
                const int s0 = R * 8 + ((2 * q + R) & 7);
                const int s1 = R * 8 + ((2 * q + 1 + R) & 7);
                uint4 ua = *reinterpret_cast<const uint4*>(As + s0 * 4);
                uint4 ub = *reinterpret_cast<const uint4*>(As + s1 * 4);
                U4B H, L;
                H.u.x = (ua.x >> 16) | (ua.y & 0xffff0000u);
                H.u.y = (ua.z >> 16) | (ua.w & 0xffff0000u);
                H.u.z = (ub.x >> 16) | (ub.y & 0xffff0000u);
                H.u.w = (ub.z >> 16) | (ub.w & 0xffff0000u);
                uint32 lw[8];
                lw[0] = __float_as_uint(__uint_as_float(ua.x) - __uint_as_float(ua.x & 0xffff0000u));
                lw[1] = __float_as_uint(__uint_as_float(ua.y) - __uint_as_float(ua.y & 0xffff0000u));
                lw[2] = __float_as_uint(__uint_as_float(ua.z) - __uint_as_float(ua.z & 0xffff0000u));
                lw[3] = __float_as_uint(__uint_as_float(ua.w) - __uint_as_float(ua.w & 0xffff0000u));
                lw[4] = __float_as_uint(__uint_as_float(ub.x) - __uint_as_float(ub.x & 0xffff0000u));
                lw[5] = __float_as_uint(__uint_as_float(ub.y) - __uint_as_float(ub.y & 0xffff0000u));
                lw[6] = __float_as_uint(__uint_as_float(ub.z) - __uint_as_float(ub.z & 0xffff0000u));
                lw[7] = __float_as_uint(__uint_as_float(ub.w) - __uint_as_float(ub.w & 0xffff0000u));
                L.u.x = (lw[0] >> 16) | (lw[1] & 0xffff0000u);
                L.u.y = (lw[2] >> 16) | (lw[3] & 0xffff0000u);
                L.u.z = (lw[4] >> 16) | (lw[5] & 0xffff0000u);
                L.u.w = (lw[6] >> 16) | (lw[7] & 0xffff0000u);
                ah[mt] = H.v; al[mt] = L.v;
            } else {
                const int s = R * 4 + ((q + R) & 3);
                ah[mt] = *reinterpret_cast<const bf16x8*>(Ahs + s * 8);
                al[mt] = *reinterpret_cast<const bf16x8*>(Als + s * 8);
            }
        }

        #pragma unroll
        for (int nt = 0; nt < 4; ++nt) {
            const int Rn = wn * 64 + nt * 16 + r;
            const int s = Rn * 4 + ((q + Rn) & 3);
            bf16x8 wh = *reinterpret_cast<const bf16x8*>(Whs + s * 8);
            bf16x8 wl = *reinterpret_cast<const bf16x8*>(Wls + s * 8);
            #pragma unroll
            for (int mt = 0; mt < 4; ++mt) {
                acc[mt][nt] = __builtin_amdgcn_mfma_f32_16x16x32_bf16(ah[mt], wh, acc[mt][nt], 0, 0, 0);
                acc[mt][nt] = __builtin_amdgcn_mfma_f32_16x16x32_bf16(ah[mt], wl, acc[mt][nt], 0, 0, 0);
                acc[mt][nt] = __builtin_amdgcn_mfma_f32_16x16x32_bf16(al[mt], wh, acc[mt][nt], 0, 0, 0);
            }
        }
    }

    if (OUT == 0) {
        #pragma unroll
        for (int nt = 0; nt < 4; ++nt) {
            const int n = n_base + wn * 64 + nt * 16 + r;
            const float bs = bias[n];
            #pragma unroll
            for (int mt = 0; mt < 4; ++mt) {
                const int m = m_base + wm * 64 + mt * 16 + q * 4;
                #pragma unroll
                for (int e = 0; e < 4; ++e)
                    C[(long)(m + e) * ldC + n] = acc[mt][nt][e] + bs;
            }
        }
    } else {
        #pragma unroll
        for (int mt = 0; mt < 4; ++mt) {
            float p[4] = {0.f, 0.f, 0.f, 0.f};
            #pragma unroll
            for (int nt = 0; nt < 4; ++nt) {
                const int n = n_base + wn * 64 + nt * 16 + r;
                const float cx = ctx[n];
                const float bs = bias[n];
                #pragma unroll
                for (int e = 0; e < 4; ++e)
                    p[e] += cx * tanhf_(acc[mt][nt][e] + bs);
            }
            #pragma unroll
            for (int mk = 1; mk < 16; mk <<= 1) {
                #pragma unroll
                for (int e = 0; e < 4; ++e) p[e] += __shfl_xor(p[e], mk, 64);
            }
            if (r == 0) {
                const int m = m_base + wm * 64 + mt * 16 + q * 4;
                #pragma unroll
                for (int e = 0; e < 4; ++e)
                    atomicAdd(&score[m + e], p[e]);
            }
        }
    }
}

// ---------------------------------------------------------------------------
// GRU recurrence, register-resident W_hh + MFMA gates.
// R8 changes: (1) xp staged into LDS via global_load_lds width-16 DMA issued
// before the MFMA phase (no VGPR cost, latency hidden by MFMA); (2) output
// stores deferred one step, packed in 8 regs, issued before MFMA so the
// vmcnt drain overlaps compute. LDS: pre 52224 + hstate 17408 + B 16384 +
// xs 49152 = 135168 B.
// ---------------------------------------------------------------------------
__global__ __launch_bounds__(512, 2)
void gru_reg(const float* __restrict__ xp,
             const unsigned short* __restrict__ Wf,
             const unsigned short* __restrict__ Wb,
             const float* __restrict__ bhf, const float* __restrict__ bhb,
             float* __restrict__ state,
             unsigned short* __restrict__ ohi, unsigned short* __restrict__ olo,
             int steps, int t0f, int t0b, int groups, int Tout)
{
    extern __shared__ char smem[];
    float* pre    = (float*)smem;                          // [768][17] f32
    float* hstate = (float*)(smem + 52224);                // [256][17] f32
    unsigned short* Bhi = (unsigned short*)(smem + 69632); // [8][64][8] bf16
    unsigned short* Blo = (unsigned short*)(smem + 77824);
    float* xs     = (float*)(smem + 86016);                // [16][768] f32

    const int tid  = threadIdx.x;
    const int lane = tid & 63;
    const int w    = tid >> 6;
    const int dir  = blockIdx.x / groups;
    const int g    = blockIdx.x % groups;
    const int nseq = groups * 16;
    const unsigned short* W = dir ? Wb : Wf;
    const float* bh = dir ? bhb : bhf;
    const int t0  = dir ? t0b : t0f;
    const int sgn = dir ? -1 : 1;

    const int j  = tid & 255;          // hidden unit for elementwise phase
    const int sh = (tid >> 8) * 8;     // seq sub-block (8 seqs)
    const float bhr = bh[j], bhz = bh[j + 256], bhn = bh[j + 512];

    // --- W_hh fragments -> registers (rows w*96 .. w*96+95) ---
    bf16x8 wf[6][8];
    {
        const int r0 = w * 96 + (lane & 15);
        const int kf = (lane >> 4) * 8;
        #pragma unroll
        for (int mt = 0; mt < 6; ++mt)
            #pragma unroll
            for (int kk = 0; kk < 8; ++kk)
                wf[mt][kk] = *reinterpret_cast<const bf16x8*>(
                    W + (long)(r0 + mt * 16) * 256 + kk * 32 + kf);
    }

    // --- init h from persistent state ---
    #pragma unroll 4
    for (int e = 0; e < 8; ++e) {
        const int s = sh + e;
        const float h0 = state[((long)dir * nseq + g * 16 + s) * 256 + j];
        hstate[j * 17 + s] = h0;
        const unsigned short hb = f2b(h0);
        const int pos = ((j >> 5) * 64 + ((j >> 3) & 3) * 16 + s) * 8 + (j & 7);
        Bhi[pos] = hb;
        Blo[pos] = f2b(h0 - b2f(hb));
    }
    __syncthreads();

    const long xdir = (long)dir * nseq * steps * 768;
    // DMA assignment: wave w loads chunks c=w*6..w*6+5; chunk c = seq c/3,
    // 256-float part c%3. Per inst: 64 lanes x 16B contiguous.
    const int dma_s = (w * 6) / 3;     // not uniform across i; computed in loop

    uint32 opack[8];
    int tprev = 0;

    for (int st = 0; st < steps; ++st) {
        const int t = t0 + sgn * st;

        // ---- 1) async DMA: xs <- xp rows for this step (h-independent) ----
        #pragma unroll
        for (int i = 0; i < 6; ++i) {
            const int c = w * 6 + i;
            const int s = c / 3, p = c % 3;            // wave-uniform
            const float* gp = xp + xdir + ((long)(g * 16 + s) * steps + st) * 768
                              + p * 256 + lane * 4;
            float* lp = xs + s * 768 + p * 256;        // wave-uniform base
            __builtin_amdgcn_global_load_lds(
                (const __attribute__((address_space(1))) void*)gp,
                (__attribute__((address_space(3))) void*)lp, 16, 0, 0);
        }

        // ---- 2) previous step's output stores (drain overlaps MFMA) ----
        if (st > 0) {
            #pragma unroll
            for (int e = 0; e < 8; ++e) {
                const int s = sh + e;
                const long orow = ((long)(g * 16 + s) * Tout + tprev) * 512 + dir * 256 + j;
                ohi[orow] = (unsigned short)(opack[e] & 0xffffu);
                olo[orow] = (unsigned short)(opack[e] >> 16);
            }
        }

        // ---- 3) MFMA phase: pre = W_hh @ h ----
        floatx4 acc[6];
        #pragma unroll
        for (int mt = 0; mt < 6; ++mt) acc[mt] = (floatx4){0.f, 0.f, 0.f, 0.f};
        #pragma unroll
        for (int kk = 0; kk < 8; ++kk) {
            bf16x8 bhv = *reinterpret_cast<const bf16x8*>(Bhi + (kk * 64 + lane) * 8);
            bf16x8 blv = *reinterpret_cast<const bf16x8*>(Blo + (kk * 64 + lane) * 8);
            #pragma unroll
            for (int mt = 0; mt < 6; ++mt) {
                acc[mt] = __builtin_amdgcn_mfma_f32_16x16x32_bf16(wf[mt][kk], bhv, acc[mt], 0, 0, 0);
                acc[mt] = __builtin_amdgcn_mfma_f32_16x16x32_bf16(wf[mt][kk], blv, acc[mt], 0, 0, 0);
            }
        }
        {
            const int q = lane >> 4, s = lane & 15;
            #pragma unroll
            for (int mt = 0; mt < 6; ++mt) {
                const int row = w * 96 + mt * 16 + q * 4;
                #pragma unroll
                for (int r_ = 0; r_ < 4; ++r_)
                    pre[(row + r_) * 17 + s] = acc[mt][r_];
            }
        }
        __syncthreads();   // drains DMA + stores (overlapped with MFMA above)

        // ---- 4) elementwise phase (x from LDS) ----
        #pragma unroll 2
        for (int e = 0; e < 8; ++e) {
            const int s = sh + e;
            const float xr = xs[s * 768 + j];
            const float xz = xs[s * 768 + 256 + j];
            const float xn = xs[s * 768 + 512 + j];
            const float pr = pre[j * 17 + s];
            const float pz = pre[(j + 256) * 17 + s];
            const float pn = pre[(j + 512) * 17 + s];
            const float hold = hstate[j * 17 + s];
            const float r  = sigmoidf_(xr + pr + bhr);
            const float z  = sigmoidf_(xz + pz + bhz);
            const float nn = tanhf_(xn + r * (pn + bhn));
            const float hnew = (1.f - z) * nn + z * hold;
            hstate[j * 17 + s] = hnew;
            const unsigned short hb = f2b(hnew);
            const unsigned short lb = f2b(hnew - b2f(hb));
            const int pos = ((j >> 5) * 64 + ((j >> 3) & 3) * 16 + s) * 8 + (j & 7);
            Bhi[pos] = hb;
            Blo[pos] = lb;
            opack[e] = (uint32)hb | ((uint32)lb << 16);
        }
        tprev = t;
        __syncthreads();
    }

    // --- final output stores + state save ---
    #pragma unroll
    for (int e = 0; e < 8; ++e) {
        const int s = sh + e;
        const long orow = ((long)(g * 16 + s) * Tout + tprev) * 512 + dir * 256 + j;
        ohi[orow] = (unsigned short)(opack[e] & 0xffffu);
        olo[orow] = (unsigned short)(opack[e] >> 16);
    }
    #pragma unroll 4
    for (int e = 0; e < 8; ++e) {
        const int s = sh + e;
        state[((long)dir * nseq + g * 16 + s) * 256 + j] = hstate[j * 17 + s];
    }
    (void)dma_s;
}

// ---------------------------------------------------------------------------
// outv[n][:] = sum_t softmax(score[n*T..])_t * feats[n*T+t][:]  (H=512, fp32)
// ---------------------------------------------------------------------------
template<int MODE>
__global__ __launch_bounds__(256)
void attn_wsum(const float* __restrict__ score,
               const unsigned short* __restrict__ fhi,
               const unsigned short* __restrict__ flo,
               void* __restrict__ o1, void* __restrict__ o2, int T)
{
    const int n = blockIdx.x;
    const int tid = threadIdx.x;
    __shared__ float a[128];
    if (tid < T) a[tid] = score[n * T + tid];
    __syncthreads();
    float mx = -1e30f;
    for (int t = 0; t < T; ++t) mx = fmaxf(mx, a[t]);
    float sm = 0.f;
    for (int t = 0; t < T; ++t) sm += __expf(a[t] - mx);
    const float inv = 1.f / sm;
    float acc0 = 0.f, acc1 = 0.f;
    for (int t = 0; t < T; ++t) {
        const float w = __expf(a[t] - mx) * inv;
        const long base = ((long)n * T + t) * 512;
        acc0 += w * (b2f(fhi[base + tid])       + b2f(flo[base + tid]));
        acc1 += w * (b2f(fhi[base + tid + 256]) + b2f(flo[base + tid + 256]));
    }
    if (MODE == 1) {
        float* o = (float*)o1;
        o[n * 512 + tid] = acc0;
        o[n * 512 + tid + 256] = acc1;
    } else {
        unsigned short* oh = (unsigned short*)o1;
        unsigned short* ol = (unsigned short*)o2;
        const unsigned short h0 = f2b(acc0), h1 = f2b(acc1);
        oh[n * 512 + tid]       = h0;  ol[n * 512 + tid]       = f2b(acc0 - b2f(h0));
        oh[n * 512 + tid + 256] = h1;  ol[n * 512 + tid + 256] = f2b(acc1 - b2f(h1));
    }
}

extern "C" void kernel_launch(void* const* d_in, const int* in_sizes, int n_in,
                              void* d_out, int out_size, void* d_ws, size_t ws_size,
                              hipStream_t stream) {
    const float* tok      = (const float*)d_in[0];
    const float* w_wih_f  = (const float*)d_in[2];
    const float* w_whh_f  = (const float*)d_in[3];
    const float* w_bih_f  = (const float*)d_in[4];
    const float* w_bhh_f  = (const float*)d_in[5];
    const float* w_wih_b  = (const float*)d_in[6];
    const float* w_whh_b  = (const float*)d_in[7];
    const float* w_bih_b  = (const float*)d_in[8];
    const float* w_bhh_b  = (const float*)d_in[9];
    const float* s_wih_f  = (const float*)d_in[10];
    const float* s_whh_f  = (const float*)d_in[11];
    const float* s_bih_f  = (const float*)d_in[12];
    const float* s_bhh_f  = (const float*)d_in[13];
    const float* s_wih_b  = (const float*)d_in[14];
    const float* s_whh_b  = (const float*)d_in[15];
    const float* s_bih_b  = (const float*)d_in[16];
    const float* s_bhh_b  = (const float*)d_in[17];
    const float* w_attn_b = (const float*)d_in[19];
    const float* w_ctx    = (const float*)d_in[20];
    const float* s_attn_b = (const float*)d_in[22];
    const float* s_ctx    = (const float*)d_in[23];

    char* ws = (char*)d_ws;
    float*          xpc   = (float*)(ws + O_XPC);
    unsigned short* owhi  = (unsigned short*)(ws + O_OWHI);
    unsigned short* owlo  = (unsigned short*)(ws + O_OWLO);
    float*          state = (float*)(ws + O_STATE);
    float*          score_w = (float*)(ws + O_SCW);
    unsigned short* W0HI  = (unsigned short*)(ws + O_W0HI);
    unsigned short* W0LO  = (unsigned short*)(ws + O_W0LO);
    unsigned short* W1HI  = (unsigned short*)(ws + O_W1HI);
    unsigned short* W1LO  = (unsigned short*)(ws + O_W1LO);
    unsigned short* WAHI  = (unsigned short*)(ws + O_WAHI);
    unsigned short* WALO  = (unsigned short*)(ws + O_WALO);
    unsigned short* S0HI  = (unsigned short*)(ws + O_S0HI);
    unsigned short* S0LO  = (unsigned short*)(ws + O_S0LO);
    unsigned short* S1HI  = (unsigned short*)(ws + O_S1HI);
    unsigned short* S1LO  = (unsigned short*)(ws + O_S1LO);
    unsigned short* SAHI  = (unsigned short*)(ws + O_SAHI);
    unsigned short* SALO  = (unsigned short*)(ws + O_SALO);
    unsigned short* HW0   = (unsigned short*)(ws + O_HW0);
    unsigned short* HW1   = (unsigned short*)(ws + O_HW1);
    unsigned short* HS0   = (unsigned short*)(ws + O_HS0);
    unsigned short* HS1   = (unsigned short*)(ws + O_HS1);
    unsigned short* senthi = (unsigned short*)(ws + O_SENTHI);
    unsigned short* sentlo = (unsigned short*)(ws + O_SENTLO);
    float*          xp_s  = (float*)(ws + O_XPS);
    float*          sstate = (float*)(ws + O_SSTATE);
    unsigned short* oshi  = (unsigned short*)(ws + O_OSHI);
    unsigned short* oslo  = (unsigned short*)(ws + O_OSLO);
    float*          score_s = (float*)(ws + O_SCS);

    const dim3 blk(256);
    const size_t GRU_LDS = 135168;  // pre 52224 + hstate 17408 + B 16384 + xs 49152

    // Zero-init: GRU h states and atomic score accumulators.
    hipMemsetAsync(ws + O_STATE,  0, 524288, stream);
    hipMemsetAsync(ws + O_SSTATE, 0, 32768, stream);
    hipMemsetAsync(ws + O_SCW,    0, 131072, stream);
    hipMemsetAsync(ws + O_SCS,    0, 1024, stream);

    // Weight prep.
    cvt_hilo6<<<dim3(1024), blk, 0, stream>>>(w_wih_f, w_wih_b, s_wih_f, s_wih_b,
                                              (const float*)d_in[18], (const float*)d_in[21], ws);
    cvt_b4<<<dim3(384), blk, 0, stream>>>(w_whh_f, w_whh_b, s_whh_f, s_whh_b, ws);

    // Word level: 4 time-chunks of 32 steps. M=8192, N=768 -> grid (6, 64).
    const long XDW = 256L * 32 * 768;
    for (int c = 0; c < 4; ++c) {
        gemm_lds<1, 0><<<dim3(6, 64), blk, 0, stream>>>(
            tok, nullptr, W0HI, W0LO, w_bih_f, xpc, 768, nullptr, nullptr,
            32 * c, 1);
        gemm_lds<1, 0><<<dim3(6, 64), blk, 0, stream>>>(
            tok, nullptr, W1HI, W1LO, w_bih_b, xpc + XDW, 768, nullptr, nullptr,
            127 - 32 * c, -1);
        gru_reg<<<dim3(32), dim3(512), GRU_LDS, stream>>>(
            xpc, HW0, HW1, w_bhh_f, w_bhh_b, state, owhi, owlo,
            32, 32 * c, 127 - 32 * c, 16, 128);
    }

    // Word attention: fused u-GEMM + tanh·ctx score, then softmax+wsum.
    gemm_lds<2, 1><<<dim3(4, 256), blk, 0, stream>>>(
        owhi, owlo, WAHI, WALO, w_attn_b, nullptr, 0, score_w, w_ctx, 0, 1);
    attn_wsum<0><<<dim3(256), blk, 0, stream>>>(score_w, owhi, owlo, senthi, sentlo, 128);

    // Sentence input gates: M=256, N=768 -> grid (6, 2).
    const long XDS = 16L * 16 * 768;
    gemm_lds<3, 0><<<dim3(6, 2), blk, 0, stream>>>(
        senthi, sentlo, S0HI, S0LO, s_bih_f, xp_s, 768, nullptr, nullptr,
        0, 1);
    gemm_lds<3, 0><<<dim3(6, 2), blk, 0, stream>>>(
        senthi, sentlo, S1HI, S1LO, s_bih_b, xp_s + XDS, 768, nullptr, nullptr,
        15, -1);

    // Sentence BiGRU: 16 seqs/dir, T=16.
    gru_reg<<<dim3(2), dim3(512), GRU_LDS, stream>>>(
        xp_s, HS0, HS1, s_bhh_f, s_bhh_b, sstate, oshi, oslo,
        16, 0, 15, 1, 16);

    // Sentence attention -> d_out (16 x 512 fp32). M=256, N=512 -> (4, 2).
    gemm_lds<2, 1><<<dim3(4, 2), blk, 0, stream>>>(
        oshi, oslo, SAHI, SALO, s_attn_b, nullptr, 0, score_s, s_ctx, 0, 1);
    attn_wsum<1><<<dim3(16), blk, 0, stream>>>(score_s, oshi, oslo, d_out, nullptr, 16);
}

// Round 9
// 1601.847 us; speedup vs baseline: 1.6683x; 1.6683x over previous
//
#include <hip/hip_runtime.h>
#include <stdint.h>

// ---------------------------------------------------------------------------
// HierarchicalReasoningEncoder on MI355X (gfx950).
// fp32 I/O. GEMMs: LDS-staged 128x128xBK32 tiles, hi/lo-split bf16 MFMA.
// Recurrence (R9): 2 seq-dirs/WG x 256 WGs (full-chip), register-resident
// W_hh (bf16) + ONE MFMA pass with hi/lo packed into B columns {0,1}/{2,3};
// h state thread-private; 3 coalesced xp loads/thread/step prefetched under
// the MFMA phase. W-bf16 remains the only numerical approximation.
// ---------------------------------------------------------------------------

using uint32  = unsigned int;
using bf16x8  = __attribute__((ext_vector_type(8))) __bf16;
using floatx4 = __attribute__((ext_vector_type(4))) float;

union U4B { uint4 u; bf16x8 v; };

__device__ __forceinline__ float b2f(unsigned short u) {
    union { uint32 i; float f; } v; v.i = ((uint32)u) << 16; return v.f;
}
__device__ __forceinline__ unsigned short f2b(float f) {
    union { float f; uint32 i; } v; v.f = f;
    uint32 r = v.i + 0x7fffu + ((v.i >> 16) & 1u);   // RNE
    return (unsigned short)(r >> 16);
}
__device__ __forceinline__ float sigmoidf_(float x) { return 1.f / (1.f + __expf(-x)); }
__device__ __forceinline__ float tanhf_(float x) {
    x = fminf(15.f, fmaxf(-15.f, x));
    float e = __expf(2.f * x);
    return (e - 1.f) / (e + 1.f);
}

// ---------------------------------------------------------------------------
// Workspace layout (bytes). Total ~130.7 MB.
// ---------------------------------------------------------------------------
#define O_XPC     0L            // 2*256*32*768*4 = 50331648 (chunked xp, fp32)
#define O_OWHI    50331648L     // 32768*512*2 = 33554432
#define O_OWLO    83886080L
#define O_STATE   117440512L    // 2*256*256*4 = 524288
#define O_SCW     117964800L    // 32768*4 = 131072
#define O_W0HI    118095872L
#define O_W0LO    118882304L
#define O_W1HI    119668736L
#define O_W1LO    120455168L
#define O_WAHI    121241600L
#define O_WALO    121765888L
#define O_S0HI    122290176L
#define O_S0LO    123076608L
#define O_S1HI    123863040L
#define O_S1LO    124649472L
#define O_SAHI    125435904L
#define O_SALO    125960192L
#define O_HW0     126484480L    // W_hh bf16 (393216 B each)
#define O_HW1     126877696L
#define O_HS0     127270912L
#define O_HS1     127664128L
#define O_SENTHI  128057344L
#define O_SENTLO  128319488L
#define O_XPS     128581632L    // 2*16*16*768*4 = 1572864
#define O_SSTATE  130154496L    // 2*16*256*4 = 32768
#define O_OSHI    130187264L
#define O_OSLO    130449408L
#define O_SCS     130711552L

// ---------------------------------------------------------------------------
// Weight prep: fp32 -> bf16 hi/lo, 6 matrices, one launch.
// ---------------------------------------------------------------------------
__global__ __launch_bounds__(256)
void cvt_hilo6(const float* __restrict__ s0, const float* __restrict__ s1,
               const float* __restrict__ s2, const float* __restrict__ s3,
               const float* __restrict__ s4, const float* __restrict__ s5,
               char* __restrict__ ws)
{
    const int b = blockIdx.x;
    const float* src; unsigned short *hi, *lo; int base;
    if (b < 192)      { src = s0; hi = (unsigned short*)(ws + O_W0HI); lo = (unsigned short*)(ws + O_W0LO); base = b; }
    else if (b < 384) { src = s1; hi = (unsigned short*)(ws + O_W1HI); lo = (unsigned short*)(ws + O_W1LO); base = b - 192; }
    else if (b < 576) { src = s2; hi = (unsigned short*)(ws + O_S0HI); lo = (unsigned short*)(ws + O_S0LO); base = b - 384; }
    else if (b < 768) { src = s3; hi = (unsigned short*)(ws + O_S1HI); lo = (unsigned short*)(ws + O_S1LO); base = b - 576; }
    else if (b < 896) { src = s4; hi = (unsigned short*)(ws + O_WAHI); lo = (unsigned short*)(ws + O_WALO); base = b - 768; }
    else              { src = s5; hi = (unsigned short*)(ws + O_SAHI); lo = (unsigned short*)(ws + O_SALO); base = b - 896; }
    const int idx = (base * 256 + threadIdx.x) * 8;
    float f[8];
    *reinterpret_cast<float4*>(&f[0]) = *reinterpret_cast<const float4*>(src + idx);
    *reinterpret_cast<float4*>(&f[4]) = *reinterpret_cast<const float4*>(src + idx + 4);
    unsigned short h[8], l[8];
    #pragma unroll
    for (int j = 0; j < 8; ++j) {
        h[j] = f2b(f[j]);
        l[j] = f2b(f[j] - b2f(h[j]));
    }
    *reinterpret_cast<uint4*>(hi + idx) = *reinterpret_cast<const uint4*>(h);
    *reinterpret_cast<uint4*>(lo + idx) = *reinterpret_cast<const uint4*>(l);
}

// W_hh fp32 -> single bf16, 4 matrices, one launch.
__global__ __launch_bounds__(256)
void cvt_b4(const float* __restrict__ s0, const float* __restrict__ s1,
            const float* __restrict__ s2, const float* __restrict__ s3,
            char* __restrict__ ws)
{
    const int b = blockIdx.x;
    const float* src; unsigned short* dst; int base;
    if (b < 96)       { src = s0; dst = (unsigned short*)(ws + O_HW0); base = b; }
    else if (b < 192) { src = s1; dst = (unsigned short*)(ws + O_HW1); base = b - 96; }
    else if (b < 288) { src = s2; dst = (unsigned short*)(ws + O_HS0); base = b - 192; }
    else              { src = s3; dst = (unsigned short*)(ws + O_HS1); base = b - 288; }
    const int idx = (base * 256 + threadIdx.x) * 8;
    float f[8];
    *reinterpret_cast<float4*>(&f[0]) = *reinterpret_cast<const float4*>(src + idx);
    *reinterpret_cast<float4*>(&f[4]) = *reinterpret_cast<const float4*>(src + idx + 4);
    unsigned short o[8];
    #pragma unroll
    for (int j = 0; j < 8; ++j) o[j] = f2b(f[j]);
    *reinterpret_cast<uint4*>(dst + idx) = *reinterpret_cast<const uint4*>(o);
}

// ---------------------------------------------------------------------------
// A-row remap (element offset into the A array, row length 512).
// ---------------------------------------------------------------------------
template<int AMODE>
__device__ __forceinline__ long amap(int m, int t0, int sgn) {
    if (AMODE == 1) {
        const int n = m >> 5, tl = m & 31;
        const int t = t0 + sgn * tl;
        return ((long)((n & 15) * 128 + t) * 16 + (n >> 4)) * 512;
    } else if (AMODE == 3) {
        const int n = m >> 4, tl = m & 15;
        return (long)(n * 16 + t0 + sgn * tl) * 512;
    }
    return (long)m * 512;
}

// ---------------------------------------------------------------------------
// LDS-staged GEMM (unchanged from R7): 128x128 tile, BK=32, 4 waves 2x2.
// ---------------------------------------------------------------------------
template<int AMODE, int OUT>
__global__ __launch_bounds__(256)
void gemm_lds(const void* __restrict__ Ap, const void* __restrict__ Ap2,
              const unsigned short* __restrict__ Whi, const unsigned short* __restrict__ Wlo,
              const float* __restrict__ bias,
              float* __restrict__ C, int ldC,
              float* __restrict__ score, const float* __restrict__ ctx,
              int t0, int sgn)
{
    __shared__ char smem_[32768];

    int bx = blockIdx.x, by = blockIdx.y;
    {
        const int nbx = gridDim.x, nby = gridDim.y;
        if ((nby & 7) == 0) {
            const int l = by * nbx + bx;      // hardware-linear id (x fastest)
            const int xcd = l & 7;
            const int s = l >> 3;
            bx = s % nbx;
            by = xcd * (nby >> 3) + s / nbx;
        }
    }

    const int tid  = threadIdx.x;
    const int lane = tid & 63;
    const int wave = tid >> 6;
    const int wm = wave >> 1, wn = wave & 1;
    const int m_base = by * 128;
    const int n_base = bx * 128;
    const int q = lane >> 4;
    const int r = lane & 15;

    float* As = (float*)smem_;
    unsigned short* Ahs = (unsigned short*)smem_;
    unsigned short* Als = (unsigned short*)(smem_ + 8192);
    unsigned short* Whs = (unsigned short*)(smem_ + 16384);
    unsigned short* Wls = (unsigned short*)(smem_ + 24576);

    int wslot[2]; long wgoff[2];
    #pragma unroll
    for (int i = 0; i < 2; ++i) {
        const int idx = tid + 256 * i;
        const int rr = idx >> 2, kg = idx & 3;
        wslot[i] = rr * 4 + ((kg + rr) & 3);
        wgoff[i] = (long)(n_base + rr) * 512 + kg * 8;
    }
    int aslot1[4]; long agoff1[4];
    int aslot2[2]; long agoff2[2];
    if (AMODE == 1) {
        #pragma unroll
        for (int i = 0; i < 4; ++i) {
            const int idx = tid + 256 * i;
            const int rr = idx >> 3, kg = idx & 7;
            aslot1[i] = rr * 8 + ((kg + rr) & 7);
            agoff1[i] = amap<AMODE>(m_base + rr, t0, sgn) + kg * 4;
        }
    } else {
        #pragma unroll
        for (int i = 0; i < 2; ++i) {
            const int idx = tid + 256 * i;
            const int rr = idx >> 2, kg = idx & 3;
            aslot2[i] = rr * 4 + ((kg + rr) & 3);
            agoff2[i] = amap<AMODE>(m_base + rr, t0, sgn) + kg * 8;
        }
    }

    floatx4 acc[4][4];
    #pragma unroll
    for (int mt = 0; mt < 4; ++mt)
        #pragma unroll
        for (int nt = 0; nt < 4; ++nt) acc[mt][nt] = (floatx4){0.f, 0.f, 0.f, 0.f};

    for (int k0 = 0; k0 < 512; k0 += 32) {
        uint4 wbh[2], wbl[2], ab[4];
        #pragma unroll
        for (int i = 0; i < 2; ++i) {
            wbh[i] = *reinterpret_cast<const uint4*>(Whi + wgoff[i] + k0);
            wbl[i] = *reinterpret_cast<const uint4*>(Wlo + wgoff[i] + k0);
        }
        if (AMODE == 1) {
            const float* A = (const float*)Ap;
            #pragma unroll
            for (int i = 0; i < 4; ++i)
                ab[i] = *reinterpret_cast<const uint4*>(A + agoff1[i] + k0);
        } else {
            const unsigned short* Ahi = (const unsigned short*)Ap;
            const unsigned short* Alo = (const unsigned short*)Ap2;
            #pragma unroll
            for (int i = 0; i < 2; ++i) {
                ab[i]     = *reinterpret_cast<const uint4*>(Ahi + agoff2[i] + k0);
                ab[2 + i] = *reinterpret_cast<const uint4*>(Alo + agoff2[i] + k0);
            }
        }
        __syncthreads();
        #pragma unroll
        for (int i = 0; i < 2; ++i) {
            *reinterpret_cast<uint4*>(Whs + wslot[i] * 8) = wbh[i];
            *reinterpret_cast<uint4*>(Wls + wslot[i] * 8) = wbl[i];
        }
        if (AMODE == 1) {
            #pragma unroll
            for (int i = 0; i < 4; ++i)
                *reinterpret_cast<uint4*>(As + aslot1[i] * 4) = ab[i];
        } else {
            #pragma unroll
            for (int i = 0; i < 2; ++i) {
                *reinterpret_cast<uint4*>(Ahs + aslot2[i] * 8) = ab[i];
                *reinterpret_cast<uint4*>(Als + aslot2[i] * 8) = ab[2 + i];
            }
        }
        __syncthreads();

        bf16x8 ah[4], al[4];
        #pragma unroll
        for (int mt = 0; mt < 4; ++mt) {
            const int R = wm * 64 + mt * 16 + r;
            if (AMODE == 1) {
                const int s0 = R * 8 + ((2 * q + R) & 7);
                const int s1 = R * 8 + ((2 * q + 1 + R) & 7);
                uint4 ua = *reinterpret_cast<const uint4*>(As + s0 * 4);
                uint4 ub = *reinterpret_cast<const uint4*>(As + s1 * 4);
                U4B H, L;
                H.u.x = (ua.x >> 16) | (ua.y & 0xffff0000u);
                H.u.y = (ua.z >> 16) | (ua.w & 0xffff0000u);
                H.u.z = (ub.x >> 16) | (ub.y & 0xffff0000u);
                H.u.w = (ub.z >> 16) | (ub.w & 0xffff0000u);
                uint32 lw[8];
                lw[0] = __float_as_uint(__uint_as_float(ua.x) - __uint_as_float(ua.x & 0xffff0000u));
                lw[1] = __float_as_uint(__uint_as_float(ua.y) - __uint_as_float(ua.y & 0xffff0000u));
                lw[2] = __float_as_uint(__uint_as_float(ua.z) - __uint_as_float(ua.z & 0xffff0000u));
                lw[3] = __float_as_uint(__uint_as_float(ua.w) - __uint_as_float(ua.w & 0xffff0000u));
                lw[4] = __float_as_uint(__uint_as_float(ub.x) - __uint_as_float(ub.x & 0xffff0000u));
                lw[5] = __float_as_uint(__uint_as_float(ub.y) - __uint_as_float(ub.y & 0xffff0000u));
                lw[6] = __float_as_uint(__uint_as_float(ub.z) - __uint_as_float(ub.z & 0xffff0000u));
                lw[7] = __float_as_uint(__uint_as_float(ub.w) - __uint_as_float(ub.w & 0xffff0000u));
                L.u.x = (lw[0] >> 16) | (lw[1] & 0xffff0000u);
                L.u.y = (lw[2] >> 16) | (lw[3] & 0xffff0000u);
                L.u.z = (lw[4] >> 16) | (lw[5] & 0xffff0000u);
                L.u.w = (lw[6] >> 16) | (lw[7] & 0xffff0000u);
                ah[mt] = H.v; al[mt] = L.v;
            } else {
                const int s = R * 4 + ((q + R) & 3);
                ah[mt] = *reinterpret_cast<const bf16x8*>(Ahs + s * 8);
                al[mt] = *reinterpret_cast<const bf16x8*>(Als + s * 8);
            }
        }

        #pragma unroll
        for (int nt = 0; nt < 4; ++nt) {
            const int Rn = wn * 64 + nt * 16 + r;
            const int s = Rn * 4 + ((q + Rn) & 3);
            bf16x8 wh = *reinterpret_cast<const bf16x8*>(Whs + s * 8);
            bf16x8 wl = *reinterpret_cast<const bf16x8*>(Wls + s * 8);
            #pragma unroll
            for (int mt = 0; mt < 4; ++mt) {
                acc[mt][nt] = __builtin_amdgcn_mfma_f32_16x16x32_bf16(ah[mt], wh, acc[mt][nt], 0, 0, 0);
                acc[mt][nt] = __builtin_amdgcn_mfma_f32_16x16x32_bf16(ah[mt], wl, acc[mt][nt], 0, 0, 0);
                acc[mt][nt] = __builtin_amdgcn_mfma_f32_16x16x32_bf16(al[mt], wh, acc[mt][nt], 0, 0, 0);
            }
        }
    }

    if (OUT == 0) {
        #pragma unroll
        for (int nt = 0; nt < 4; ++nt) {
            const int n = n_base + wn * 64 + nt * 16 + r;
            const float bs = bias[n];
            #pragma unroll
            for (int mt = 0; mt < 4; ++mt) {
                const int m = m_base + wm * 64 + mt * 16 + q * 4;
                #pragma unroll
                for (int e = 0; e < 4; ++e)
                    C[(long)(m + e) * ldC + n] = acc[mt][nt][e] + bs;
            }
        }
    } else {
        #pragma unroll
        for (int mt = 0; mt < 4; ++mt) {
            float p[4] = {0.f, 0.f, 0.f, 0.f};
            #pragma unroll
            for (int nt = 0; nt < 4; ++nt) {
                const int n = n_base + wn * 64 + nt * 16 + r;
                const float cx = ctx[n];
                const float bs = bias[n];
                #pragma unroll
                for (int e = 0; e < 4; ++e)
                    p[e] += cx * tanhf_(acc[mt][nt][e] + bs);
            }
            #pragma unroll
            for (int mk = 1; mk < 16; mk <<= 1) {
                #pragma unroll
                for (int e = 0; e < 4; ++e) p[e] += __shfl_xor(p[e], mk, 64);
            }
            if (r == 0) {
                const int m = m_base + wm * 64 + mt * 16 + q * 4;
                #pragma unroll
                for (int e = 0; e < 4; ++e)
                    atomicAdd(&score[m + e], p[e]);
            }
        }
    }
}

// ---------------------------------------------------------------------------
// GRU recurrence (R9): 2 seq-dirs per WG, 512 thr = 8 waves, 256 WGs word-
// level. Wave w holds W_hh rows [w*96, w*96+96) as 48 A-fragments. Per step,
// ONE MFMA pass with B cols {0,1}=h_hi(seq0,1), {2,3}=h_lo -> pre[768][4];
// elementwise sums cols s and 2+s. h is thread-private (thread = (s, j)).
// xp: 3 coalesced loads/thread issued at step-top, consumed after the MFMA
// phase (latency hidden). Chunk-persistent h state in global.
// ---------------------------------------------------------------------------
__global__ __launch_bounds__(512, 2)
void gru2(const float* __restrict__ xp,
          const unsigned short* __restrict__ Wf,
          const unsigned short* __restrict__ Wb,
          const float* __restrict__ bhf, const float* __restrict__ bhb,
          float* __restrict__ state,
          unsigned short* __restrict__ ohi, unsigned short* __restrict__ olo,
          int steps, int t0f, int t0b, int groups, int Tout)
{
    __shared__ float pre[768 * 5];          // cols 0..3 at stride 5 (15360 B)
    __shared__ unsigned short Bf[8 * 64 * 8]; // B fragments (8192 B)

    const int tid  = threadIdx.x;
    const int lane = tid & 63;
    const int w    = tid >> 6;
    const int dir  = blockIdx.x / groups;
    const int g    = blockIdx.x % groups;
    const int nseq = groups * 2;
    const unsigned short* W = dir ? Wb : Wf;
    const float* bh = dir ? bhb : bhf;
    const int t0  = dir ? t0b : t0f;
    const int sgn = dir ? -1 : 1;

    const int s = tid >> 8;            // seq within WG (0..1)
    const int j = tid & 255;           // hidden unit
    const float bhr = bh[j], bhz = bh[j + 256], bhn = bh[j + 512];

    // --- W_hh fragments -> registers (rows w*96 .. w*96+95) ---
    bf16x8 wf[6][8];
    {
        const int r0 = w * 96 + (lane & 15);
        const int kf = (lane >> 4) * 8;
        #pragma unroll
        for (int mt = 0; mt < 6; ++mt)
            #pragma unroll
            for (int kk = 0; kk < 8; ++kk)
                wf[mt][kk] = *reinterpret_cast<const bf16x8*>(
                    W + (long)(r0 + mt * 16) * 256 + kk * 32 + kf);
    }

    // --- zero Bf (cols >=4 stay zero forever), init h ---
    #pragma unroll
    for (int i = 0; i < 4; ++i)
        reinterpret_cast<uint32*>(Bf)[tid * 4 + i] = 0;

    float h = state[((long)dir * nseq + g * 2 + s) * 256 + j];
    const int posHi = ((j >> 5) * 64 + ((j >> 3) & 3) * 16 + s) * 8 + (j & 7);
    const int posLo = ((j >> 5) * 64 + ((j >> 3) & 3) * 16 + 2 + s) * 8 + (j & 7);
    {
        const unsigned short hb = f2b(h);
        Bf[posHi] = hb;
        Bf[posLo] = f2b(h - b2f(hb));
    }
    __syncthreads();

    const float* xbase = xp + (long)dir * nseq * steps * 768
                       + (long)(g * 2 + s) * steps * 768;
    const int q = lane >> 4, r = lane & 15;

    for (int st = 0; st < steps; ++st) {
        const int t = t0 + sgn * st;

        // ---- prefetch x (consumed after the MFMA phase) ----
        const float* xb = xbase + (long)st * 768;
        const float xr = xb[j];
        const float xz = xb[256 + j];
        const float xn = xb[512 + j];

        // ---- MFMA phase: pre[row][0..3] = W_hh @ [h_hi | h_lo] ----
        floatx4 acc[6];
        #pragma unroll
        for (int mt = 0; mt < 6; ++mt) acc[mt] = (floatx4){0.f, 0.f, 0.f, 0.f};
        #pragma unroll
        for (int kk = 0; kk < 8; ++kk) {
            bf16x8 bv = *reinterpret_cast<const bf16x8*>(Bf + (kk * 64 + lane) * 8);
            #pragma unroll
            for (int mt = 0; mt < 6; ++mt)
                acc[mt] = __builtin_amdgcn_mfma_f32_16x16x32_bf16(wf[mt][kk], bv, acc[mt], 0, 0, 0);
        }
        if (r < 4) {
            #pragma unroll
            for (int mt = 0; mt < 6; ++mt) {
                const int row = w * 96 + mt * 16 + q * 4;
                #pragma unroll
                for (int e = 0; e < 4; ++e)
                    pre[(row + e) * 5 + r] = acc[mt][e];
            }
        }
        __syncthreads();

        // ---- elementwise: one gate-triple per thread ----
        {
            const float pr = pre[j * 5 + s]         + pre[j * 5 + 2 + s];
            const float pz = pre[(j + 256) * 5 + s] + pre[(j + 256) * 5 + 2 + s];
            const float pn = pre[(j + 512) * 5 + s] + pre[(j + 512) * 5 + 2 + s];
            const float rg = sigmoidf_(xr + pr + bhr);
            const float zg = sigmoidf_(xz + pz + bhz);
            const float nn = tanhf_(xn + rg * (pn + bhn));
            h = (1.f - zg) * nn + zg * h;
            const unsigned short hb = f2b(h);
            const unsigned short lb = f2b(h - b2f(hb));
            Bf[posHi] = hb;
            Bf[posLo] = lb;
            const long orow = ((long)(g * 2 + s) * Tout + t) * 512 + dir * 256 + j;
            ohi[orow] = hb;
            olo[orow] = lb;
        }
        __syncthreads();
    }

    state[((long)dir * nseq + g * 2 + s) * 256 + j] = h;
}

// ---------------------------------------------------------------------------
// outv[n][:] = sum_t softmax(score[n*T..])_t * feats[n*T+t][:]  (H=512, fp32)
// ---------------------------------------------------------------------------
template<int MODE>
__global__ __launch_bounds__(256)
void attn_wsum(const float* __restrict__ score,
               const unsigned short* __restrict__ fhi,
               const unsigned short* __restrict__ flo,
               void* __restrict__ o1, void* __restrict__ o2, int T)
{
    const int n = blockIdx.x;
    const int tid = threadIdx.x;
    __shared__ float a[128];
    if (tid < T) a[tid] = score[n * T + tid];
    __syncthreads();
    float mx = -1e30f;
    for (int t = 0; t < T; ++t) mx = fmaxf(mx, a[t]);
    float sm = 0.f;
    for (int t = 0; t < T; ++t) sm += __expf(a[t] - mx);
    const float inv = 1.f / sm;
    float acc0 = 0.f, acc1 = 0.f;
    for (int t = 0; t < T; ++t) {
        const float w = __expf(a[t] - mx) * inv;
        const long base = ((long)n * T + t) * 512;
        acc0 += w * (b2f(fhi[base + tid])       + b2f(flo[base + tid]));
        acc1 += w * (b2f(fhi[base + tid + 256]) + b2f(flo[base + tid + 256]));
    }
    if (MODE == 1) {
        float* o = (float*)o1;
        o[n * 512 + tid] = acc0;
        o[n * 512 + tid + 256] = acc1;
    } else {
        unsigned short* oh = (unsigned short*)o1;
        unsigned short* ol = (unsigned short*)o2;
        const unsigned short h0 = f2b(acc0), h1 = f2b(acc1);
        oh[n * 512 + tid]       = h0;  ol[n * 512 + tid]       = f2b(acc0 - b2f(h0));
        oh[n * 512 + tid + 256] = h1;  ol[n * 512 + tid + 256] = f2b(acc1 - b2f(h1));
    }
}

extern "C" void kernel_launch(void* const* d_in, const int* in_sizes, int n_in,
                              void* d_out, int out_size, void* d_ws, size_t ws_size,
                              hipStream_t stream) {
    const float* tok      = (const float*)d_in[0];
    const float* w_wih_f  = (const float*)d_in[2];
    const float* w_whh_f  = (const float*)d_in[3];
    const float* w_bih_f  = (const float*)d_in[4];
    const float* w_bhh_f  = (const float*)d_in[5];
    const float* w_wih_b  = (const float*)d_in[6];
    const float* w_whh_b  = (const float*)d_in[7];
    const float* w_bih_b  = (const float*)d_in[8];
    const float* w_bhh_b  = (const float*)d_in[9];
    const float* s_wih_f  = (const float*)d_in[10];
    const float* s_whh_f  = (const float*)d_in[11];
    const float* s_bih_f  = (const float*)d_in[12];
    const float* s_bhh_f  = (const float*)d_in[13];
    const float* s_wih_b  = (const float*)d_in[14];
    const float* s_whh_b  = (const float*)d_in[15];
    const float* s_bih_b  = (const float*)d_in[16];
    const float* s_bhh_b  = (const float*)d_in[17];
    const float* w_attn_b = (const float*)d_in[19];
    const float* w_ctx    = (const float*)d_in[20];
    const float* s_attn_b = (const float*)d_in[22];
    const float* s_ctx    = (const float*)d_in[23];

    char* ws = (char*)d_ws;
    float*          xpc   = (float*)(ws + O_XPC);
    unsigned short* owhi  = (unsigned short*)(ws + O_OWHI);
    unsigned short* owlo  = (unsigned short*)(ws + O_OWLO);
    float*          state = (float*)(ws + O_STATE);
    float*          score_w = (float*)(ws + O_SCW);
    unsigned short* W0HI  = (unsigned short*)(ws + O_W0HI);
    unsigned short* W0LO  = (unsigned short*)(ws + O_W0LO);
    unsigned short* W1HI  = (unsigned short*)(ws + O_W1HI);
    unsigned short* W1LO  = (unsigned short*)(ws + O_W1LO);
    unsigned short* WAHI  = (unsigned short*)(ws + O_WAHI);
    unsigned short* WALO  = (unsigned short*)(ws + O_WALO);
    unsigned short* S0HI  = (unsigned short*)(ws + O_S0HI);
    unsigned short* S0LO  = (unsigned short*)(ws + O_S0LO);
    unsigned short* S1HI  = (unsigned short*)(ws + O_S1HI);
    unsigned short* S1LO  = (unsigned short*)(ws + O_S1LO);
    unsigned short* SAHI  = (unsigned short*)(ws + O_SAHI);
    unsigned short* SALO  = (unsigned short*)(ws + O_SALO);
    unsigned short* HW0   = (unsigned short*)(ws + O_HW0);
    unsigned short* HW1   = (unsigned short*)(ws + O_HW1);
    unsigned short* HS0   = (unsigned short*)(ws + O_HS0);
    unsigned short* HS1   = (unsigned short*)(ws + O_HS1);
    unsigned short* senthi = (unsigned short*)(ws + O_SENTHI);
    unsigned short* sentlo = (unsigned short*)(ws + O_SENTLO);
    float*          xp_s  = (float*)(ws + O_XPS);
    float*          sstate = (float*)(ws + O_SSTATE);
    unsigned short* oshi  = (unsigned short*)(ws + O_OSHI);
    unsigned short* oslo  = (unsigned short*)(ws + O_OSLO);
    float*          score_s = (float*)(ws + O_SCS);

    const dim3 blk(256);

    // Zero-init: GRU h states and atomic score accumulators.
    hipMemsetAsync(ws + O_STATE,  0, 524288, stream);
    hipMemsetAsync(ws + O_SSTATE, 0, 32768, stream);
    hipMemsetAsync(ws + O_SCW,    0, 131072, stream);
    hipMemsetAsync(ws + O_SCS,    0, 1024, stream);

    // Weight prep.
    cvt_hilo6<<<dim3(1024), blk, 0, stream>>>(w_wih_f, w_wih_b, s_wih_f, s_wih_b,
                                              (const float*)d_in[18], (const float*)d_in[21], ws);
    cvt_b4<<<dim3(384), blk, 0, stream>>>(w_whh_f, w_whh_b, s_whh_f, s_whh_b, ws);

    // Word level: 4 time-chunks of 32 steps. M=8192, N=768 -> grid (6, 64).
    const long XDW = 256L * 32 * 768;
    for (int c = 0; c < 4; ++c) {
        gemm_lds<1, 0><<<dim3(6, 64), blk, 0, stream>>>(
            tok, nullptr, W0HI, W0LO, w_bih_f, xpc, 768, nullptr, nullptr,
            32 * c, 1);
        gemm_lds<1, 0><<<dim3(6, 64), blk, 0, stream>>>(
            tok, nullptr, W1HI, W1LO, w_bih_b, xpc + XDW, 768, nullptr, nullptr,
            127 - 32 * c, -1);
        gru2<<<dim3(256), dim3(512), 0, stream>>>(
            xpc, HW0, HW1, w_bhh_f, w_bhh_b, state, owhi, owlo,
            32, 32 * c, 127 - 32 * c, 128, 128);
    }

    // Word attention: fused u-GEMM + tanh·ctx score, then softmax+wsum.
    gemm_lds<2, 1><<<dim3(4, 256), blk, 0, stream>>>(
        owhi, owlo, WAHI, WALO, w_attn_b, nullptr, 0, score_w, w_ctx, 0, 1);
    attn_wsum<0><<<dim3(256), blk, 0, stream>>>(score_w, owhi, owlo, senthi, sentlo, 128);

    // Sentence input gates: M=256, N=768 -> grid (6, 2).
    const long XDS = 16L * 16 * 768;
    gemm_lds<3, 0><<<dim3(6, 2), blk, 0, stream>>>(
        senthi, sentlo, S0HI, S0LO, s_bih_f, xp_s, 768, nullptr, nullptr,
        0, 1);
    gemm_lds<3, 0><<<dim3(6, 2), blk, 0, stream>>>(
        senthi, sentlo, S1HI, S1LO, s_bih_b, xp_s + XDS, 768, nullptr, nullptr,
        15, -1);

    // Sentence BiGRU: 16 seqs/dir, T=16; 2 seqs/WG -> grid 16.
    gru2<<<dim3(16), dim3(512), 0, stream>>>(
        xp_s, HS0, HS1, s_bhh_f, s_bhh_b, sstate, oshi, oslo,
        16, 0, 15, 8, 16);

    // Sentence attention -> d_out (16 x 512 fp32). M=256, N=512 -> (4, 2).
    gemm_lds<2, 1><<<dim3(4, 2), blk, 0, stream>>>(
        oshi, oslo, SAHI, SALO, s_attn_b, nullptr, 0, score_s, s_ctx, 0, 1);
    attn_wsum<1><<<dim3(16), blk, 0, stream>>>(score_s, oshi, oslo, d_out, nullptr, 16);
}